// Round 19
// baseline (929.264 us; speedup 1.0000x reference)
//
#include <hip/hip_runtime.h>
#include <math.h>

#define Bn   16
#define Nn   4096
#define Cn   64
#define Mn   1024
#define Kn   32
#define OUTn 128
#define EPS  1e-5f

typedef unsigned long long u64;
typedef unsigned int u32;
typedef unsigned short u16;
typedef __attribute__((ext_vector_type(8))) short bf16x8;
typedef __attribute__((ext_vector_type(4))) float f32x4;

__device__ __forceinline__ u64 u64min(u64 a, u64 b) { return a < b ? a : b; }
__device__ __forceinline__ u64 u64max(u64 a, u64 b) { return a > b ? a : b; }

template<int CTRL>
__device__ __forceinline__ u64 dpp_u64(u64 x) {
  union { u64 q; u32 w[2]; } in, out;
  in.q = x;
  out.w[0] = (u32)__builtin_amdgcn_update_dpp((int)in.w[0], (int)in.w[0], CTRL, 0xf, 0xf, false);
  out.w[1] = (u32)__builtin_amdgcn_update_dpp((int)in.w[1], (int)in.w[1], CTRL, 0xf, 0xf, false);
  return out.q;
}
// f32 DPP move (old = x). row_ror:N = 0x120|N within 16-lane rows.
template<int CTRL>
__device__ __forceinline__ float dpp_f32(float x) {
  return __uint_as_float((u32)__builtin_amdgcn_update_dpp(
      (int)__float_as_uint(x), (int)__float_as_uint(x), CTRL, 0xf, 0xf, false));
}

__device__ __forceinline__ u64 wave_max_dpp(u64 v) {
  v = u64max(v, dpp_u64<0x111>(v));
  v = u64max(v, dpp_u64<0x112>(v));
  v = u64max(v, dpp_u64<0x114>(v));
  v = u64max(v, dpp_u64<0x118>(v));
  v = u64max(v, dpp_u64<0x142>(v));
  v = u64max(v, dpp_u64<0x143>(v));
  return v;
}
__device__ __forceinline__ u64 wave_min_dpp(u64 v) {
  v = u64min(v, dpp_u64<0x111>(v));
  v = u64min(v, dpp_u64<0x112>(v));
  v = u64min(v, dpp_u64<0x114>(v));
  v = u64min(v, dpp_u64<0x118>(v));
  v = u64min(v, dpp_u64<0x142>(v));
  v = u64min(v, dpp_u64<0x143>(v));
  return v;
}

// RTN f32->bf16 pack helpers
__device__ __forceinline__ u32 rnd2(float a, float b) {
  u32 ua = __float_as_uint(a);
  ua = (ua + 0x7FFFu + ((ua >> 16) & 1u)) >> 16;
  u32 ub = __float_as_uint(b);
  ub = (ub + 0x7FFFu + ((ub >> 16) & 1u)) & 0xFFFF0000u;
  return ua | ub;
}
__device__ __forceinline__ u16 bf16s(float a) {
  u32 ua = __float_as_uint(a);
  return (u16)((ua + 0x7FFFu + ((ua >> 16) & 1u)) >> 16);
}

// ---------------------------------------------------------------------------
// prep: merged wconv (weights f32->bf16 RTN, fragment k-order) + pconv
// (xyz -> float4, exact copies). One launch instead of two.
//   wb layout (bf16): [0,6144) W1k[64][96]; [6144,10240) W2; [10240,18432) Wout
// ---------------------------------------------------------------------------
#define WB_N   18432
#define P4_N   (Bn * Nn)
__global__ __launch_bounds__(256) void prep_kernel(
    const float* __restrict__ W1, const float* __restrict__ W2,
    const float* __restrict__ Wout, u16* __restrict__ wb,
    const float* __restrict__ xyz, float4* __restrict__ p4)
{
  const int i = blockIdx.x * 256 + threadIdx.x;
  if (i < WB_N) {
    float v;
    if (i < 6144) {
      const int r = i / 96, k = i % 96;
      v = (k < 64) ? W1[r * 67 + 3 + k] : (k < 67 ? W1[r * 67 + (k - 64)] : 0.0f);
    } else if (i < 10240) {
      v = W2[i - 6144];
    } else {
      v = Wout[i - 10240];
    }
    wb[i] = bf16s(v);
  } else {
    const int j = i - WB_N;
    if (j < P4_N)
      p4[j] = make_float4(xyz[3*j+0], xyz[3*j+1], xyz[3*j+2], 0.0f);
  }
}

// ---------------------------------------------------------------------------
// FPS: r13 steady-state loop byte-identical (measured floor 647us across 5
// restructures). Only the LDS fill changed: coalesced dwordx4 from p4
// (exact copies -> bit-identical selection).
// ---------------------------------------------------------------------------
__global__ __launch_bounds__(256) void fps_kernel(
    const float4* __restrict__ p4, float* __restrict__ cent)
{
  __shared__ float4 pts4[Nn];          // 64 KB
  __shared__ __align__(16) u64 pvq[2][4];

  const int b = blockIdx.x;
  const int t = threadIdx.x;
  const float4* src = p4 + (size_t)b * Nn;

  for (int i = t; i < Nn; i += 256) pts4[i] = src[i];
  __syncthreads();

  const float4 c0 = pts4[0];

  float px[16], py[16], pz[16], d[16];
  u32 ninv[16];
#pragma unroll
  for (int j = 0; j < 16; ++j) {
    const int n = j * 256 + t;
    ninv[j] = (u32)(~n);
    const float4 p = pts4[n];
    px[j] = p.x; py[j] = p.y; pz[j] = p.z;
    const float dx = px[j] - c0.x, dy = py[j] - c0.y, dz = pz[j] - c0.z;
    d[j] = (dx * dx + dy * dy) + dz * dz;
  }

  if (t == 0) {
    float* o = cent + (size_t)b * Mn * 3;
    o[0] = c0.x; o[1] = c0.y; o[2] = c0.z;
  }

  for (int m = 1; m < Mn; ++m) {
    u64 k[16];
#pragma unroll
    for (int j = 0; j < 16; ++j)
      k[j] = ((u64)__float_as_uint(d[j]) << 32) | ninv[j];
#pragma unroll
    for (int st = 1; st < 16; st <<= 1)
#pragma unroll
      for (int j = 0; j < 16; j += (st << 1))
        k[j] = u64max(k[j], k[j + st]);

    const u64 bk = wave_max_dpp(k[0]);
    const int par = m & 1;
    if ((t & 63) == 63) pvq[par][t >> 6] = bk;
    __syncthreads();

    const u64 f = u64max(u64max(pvq[par][0], pvq[par][1]),
                         u64max(pvq[par][2], pvq[par][3]));
    const int fi = (int)(~(u32)f);

    const float4 cp = pts4[fi];
    if (t == 0) {
      float* o = cent + ((size_t)b * Mn + m) * 3;
      o[0] = cp.x; o[1] = cp.y; o[2] = cp.z;
    }

#pragma unroll
    for (int j = 0; j < 16; ++j) {
      const float dx = px[j] - cp.x, dy = py[j] - cp.y, dz = pz[j] - cp.z;
      const float nd = (dx * dx + dy * dy) + dz * dz;
      d[j] = fminf(d[j], nd);
    }
  }
}

// ---------------------------------------------------------------------------
// KNN: r18 knn4 version, byte-identical (one wave/centroid, float4 points,
// zero LDS, zero barriers).
// ---------------------------------------------------------------------------
__global__ __launch_bounds__(256) void knn4_kernel(
    const float4* __restrict__ p4, const float* __restrict__ cent,
    int* __restrict__ osel)
{
  const int t    = threadIdx.x;
  const int lane = t & 63;
  const int wid  = __builtin_amdgcn_readfirstlane(t >> 6);
  const int g    = (blockIdx.x << 2) + wid;
  const int b    = g >> 10;
  const float4* P4 = p4 + (size_t)b * Nn;

  const float cx = cent[(size_t)g * 3 + 0];
  const float cy = cent[(size_t)g * 3 + 1];
  const float cz = cent[(size_t)g * 3 + 2];
  const float cc2 = (cx * cx + cy * cy) + cz * cz;

  u64 kk[4][16];
  u64 gm0, gm1, gm2, gm3;

#pragma unroll
  for (int grp = 0; grp < 4; ++grp) {
#pragma unroll
    for (int j = 0; j < 16; ++j) {
      const int n = grp * 1024 + j * 64 + lane;
      const float4 p = P4[n];
      const float x = p.x, y = p.y, z = p.z;
      const float pp = (x * x + y * y) + z * z;
      const float dt = (cx * x + cy * y) + cz * z;
      const float d2 = (cc2 + pp) - 2.0f * dt;
      const u32 bu = __float_as_uint(d2);
      const u32 mo = bu ^ (0x80000000u | (u32)((int)bu >> 31));
      kk[grp][j] = ((u64)mo << 32) | (u32)n;
    }
  }
#define TREE16(dst, A_)                                                 \
  {                                                                     \
    u64 t0 = u64min(A_[0], A_[1]),  t1 = u64min(A_[2], A_[3]);          \
    u64 t2 = u64min(A_[4], A_[5]),  t3 = u64min(A_[6], A_[7]);          \
    u64 t4 = u64min(A_[8], A_[9]),  t5 = u64min(A_[10], A_[11]);        \
    u64 t6 = u64min(A_[12], A_[13]), t7 = u64min(A_[14], A_[15]);       \
    t0 = u64min(t0, t1); t2 = u64min(t2, t3);                           \
    t4 = u64min(t4, t5); t6 = u64min(t6, t7);                           \
    dst = u64min(u64min(t0, t2), u64min(t4, t6));                       \
  }
  TREE16(gm0, kk[0]); TREE16(gm1, kk[1]);
  TREE16(gm2, kk[2]); TREE16(gm3, kk[3]);
  u64 bk = u64min(u64min(gm0, gm1), u64min(gm2, gm3));

  int myfi = 0;
  for (int s = 0; s < Kn; ++s) {
    const u64 v = wave_min_dpp(bk);
    const u32 flo = (u32)__builtin_amdgcn_readlane((int)(u32)v, 63);
    const int fi = (int)flo;
    if (lane == s) myfi = fi;

    const int og = __builtin_amdgcn_readfirstlane(fi >> 10);
    const int oj = __builtin_amdgcn_readfirstlane((fi >> 6) & 15);
    if (lane == (fi & 63)) {
#pragma unroll
      for (int grp = 0; grp < 4; ++grp) {
        if (grp == og) {
#pragma unroll
          for (int j = 0; j < 16; ++j)
            if (j == oj) kk[grp][j] = ~0ull;
          u64 nm;
          TREE16(nm, kk[grp]);
          if (grp == 0) gm0 = nm;
          else if (grp == 1) gm1 = nm;
          else if (grp == 2) gm2 = nm;
          else gm3 = nm;
        }
      }
      bk = u64min(u64min(gm0, gm1), u64min(gm2, gm3));
    }
  }
#undef TREE16

  if (lane < Kn) osel[(size_t)g * 128 + lane] = myfi;
}

// ---------------------------------------------------------------------------
// MLP via bf16 MFMA (r18 structure + DPP LN). Changes: (a) L1 weight
// fragments prefetched into registers BEFORE __syncthreads (compiler cannot
// hoist loads across the barrier; their ~500cy latency now hides under
// gather+barrier); (b) gather coords from p4 (one float4 vs 3 scalars).
// All arithmetic bit-identical to r18.
// ---------------------------------------------------------------------------
__global__ __launch_bounds__(256) void mlp_kernel(
    const float4* __restrict__ p4, const float* __restrict__ feat,
    const u16* __restrict__ wb,
    const float* __restrict__ b1, const float* __restrict__ g1,
    const float* __restrict__ be1,
    const float* __restrict__ b2, const float* __restrict__ g2,
    const float* __restrict__ be2, const float* __restrict__ bout,
    const float* __restrict__ cent, float* __restrict__ out)
{
  __shared__ u32 Xw[128][52];        // 128 rows x 104 bf16 (26.6 KB)

  const int g0   = blockIdx.x << 2;
  const int b    = g0 >> 10;
  const int t    = threadIdx.x;
  const int wid  = __builtin_amdgcn_readfirstlane(t >> 6);
  const int lane = t & 63;

  const float4* P4 = p4 + (size_t)b * Nn;
  const float* F = feat + (size_t)b * Nn * Cn;
  const int* osel = (const int*)out;

  const u16* w1b = wb;               // [64][96]
  const u16* w2b = wb + 6144;        // [64][64]
  const u16* w3b = wb + 10240;       // [128][64]

  const int c  = lane & 15;          // frag col / A-row low
  const int gq = lane >> 4;          // frag k-group / C-row group
  const int R0 = wid << 5;           // wave's first row (centroid wid)

  // ---- prefetch L1 weight fragments (LDS-independent) ----
  bf16x8 w1f[4][3];
#pragma unroll
  for (int nt = 0; nt < 4; ++nt)
#pragma unroll
    for (int ks = 0; ks < 3; ++ks)
      w1f[nt][ks] = *(const bf16x8*)(w1b + (16*nt + c) * 96 + 32*ks + 8*gq);

  // ---- gather -> bf16 LDS (2 threads per row) ----
  {
    const int row = t >> 1, half = t & 1;
    const int gi = g0 + (row >> 5);
    const int n = osel[(size_t)gi * 128 + (row & 31)];
    const float* fr = F + (size_t)n * Cn + 32 * half;
#pragma unroll
    for (int q = 0; q < 4; ++q) {
      const float4 a = ((const float4*)fr)[2*q];
      const float4 cc = ((const float4*)fr)[2*q+1];
      uint4 wv;
      wv.x = rnd2(a.x, a.y); wv.y = rnd2(a.z, a.w);
      wv.z = rnd2(cc.x, cc.y); wv.w = rnd2(cc.z, cc.w);
      *(uint4*)&Xw[row][16*half + 4*q] = wv;
    }
    if (half) {
      const float4 pv = P4[n];
      const float pxc = pv.x - cent[(size_t)gi*3+0];
      const float pyc = pv.y - cent[(size_t)gi*3+1];
      const float pzc = pv.z - cent[(size_t)gi*3+2];
      Xw[row][32] = rnd2(pxc, pyc);
      Xw[row][33] = rnd2(pzc, 0.0f);
      Xw[row][34] = 0; Xw[row][35] = 0;
#pragma unroll
      for (int q2 = 0; q2 < 4; ++q2) {
        uint4 z; z.x = z.y = z.z = z.w = 0;
        *(uint4*)&Xw[row][36 + 4*q2] = z;
      }
    }
  }
  __syncthreads();

  const short* xs_base = (const short*)Xw;

  f32x4 acc[2][4];

  // ================= layer 1: K=96 (feats | coords | pad) ==============
#pragma unroll
  for (int nt = 0; nt < 4; ++nt) {
    const float bv = b1[16*nt + c];
    acc[0][nt] = (f32x4){bv, bv, bv, bv};
    acc[1][nt] = (f32x4){bv, bv, bv, bv};
  }
#pragma unroll
  for (int ks = 0; ks < 3; ++ks) {
    const bf16x8 af0 = *(const bf16x8*)(xs_base + (R0 +      c) * 104 + 32*ks + 8*gq);
    const bf16x8 af1 = *(const bf16x8*)(xs_base + (R0 + 16 + c) * 104 + 32*ks + 8*gq);
#pragma unroll
    for (int nt = 0; nt < 4; ++nt) {
      acc[0][nt] = __builtin_amdgcn_mfma_f32_16x16x32_bf16(af0, w1f[nt][ks], acc[0][nt], 0, 0, 0);
      acc[1][nt] = __builtin_amdgcn_mfma_f32_16x16x32_bf16(af1, w1f[nt][ks], acc[1][nt], 0, 0, 0);
    }
  }

  // ---- LN1 + ReLU (DPP rotation allreduce) -> Xw bf16 cols 0..63 ----
  {
    float gg[4], bb[4];
#pragma unroll
    for (int nt = 0; nt < 4; ++nt) { gg[nt] = g1[16*nt + c]; bb[nt] = be1[16*nt + c]; }
#pragma unroll
    for (int mt = 0; mt < 2; ++mt) {
#pragma unroll
      for (int r = 0; r < 4; ++r) {
        const float v0 = acc[mt][0][r], v1 = acc[mt][1][r];
        const float v2 = acc[mt][2][r], v3 = acc[mt][3][r];
        float s = (v0 + v1) + (v2 + v3);
        float q = fmaf(v0, v0, fmaf(v1, v1, fmaf(v2, v2, v3 * v3)));
        s += dpp_f32<0x128>(s); q += dpp_f32<0x128>(q);   // row_ror:8
        s += dpp_f32<0x124>(s); q += dpp_f32<0x124>(q);   // row_ror:4
        s += dpp_f32<0x122>(s); q += dpp_f32<0x122>(q);   // row_ror:2
        s += dpp_f32<0x121>(s); q += dpp_f32<0x121>(q);   // row_ror:1
        const float mu = s * 0.015625f;
        const float var = q * 0.015625f - mu * mu;
        const float rs = rsqrtf(var + EPS);
        const int row = R0 + 16*mt + 4*gq + r;
        short* xsw = (short*)Xw + row * 104;
#pragma unroll
        for (int nt = 0; nt < 4; ++nt) {
          const float y = fmaxf((acc[mt][nt][r] - mu) * rs * gg[nt] + bb[nt], 0.0f);
          xsw[16*nt + c] = (short)bf16s(y);
        }
      }
    }
  }

  // ================= layer 2: K=64 =================
#pragma unroll
  for (int nt = 0; nt < 4; ++nt) {
    const float bv = b2[16*nt + c];
    acc[0][nt] = (f32x4){bv, bv, bv, bv};
    acc[1][nt] = (f32x4){bv, bv, bv, bv};
  }
#pragma unroll
  for (int ks = 0; ks < 2; ++ks) {
    const bf16x8 af0 = *(const bf16x8*)(xs_base + (R0 +      c) * 104 + 32*ks + 8*gq);
    const bf16x8 af1 = *(const bf16x8*)(xs_base + (R0 + 16 + c) * 104 + 32*ks + 8*gq);
#pragma unroll
    for (int nt = 0; nt < 4; ++nt) {
      const bf16x8 bf = *(const bf16x8*)(w2b + (16*nt + c) * 64 + 32*ks + 8*gq);
      acc[0][nt] = __builtin_amdgcn_mfma_f32_16x16x32_bf16(af0, bf, acc[0][nt], 0, 0, 0);
      acc[1][nt] = __builtin_amdgcn_mfma_f32_16x16x32_bf16(af1, bf, acc[1][nt], 0, 0, 0);
    }
  }

  // ---- LN2 + ReLU (DPP rotation allreduce) -> Xw bf16 cols 0..63 ----
  {
    float gg[4], bb[4];
#pragma unroll
    for (int nt = 0; nt < 4; ++nt) { gg[nt] = g2[16*nt + c]; bb[nt] = be2[16*nt + c]; }
#pragma unroll
    for (int mt = 0; mt < 2; ++mt) {
#pragma unroll
      for (int r = 0; r < 4; ++r) {
        const float v0 = acc[mt][0][r], v1 = acc[mt][1][r];
        const float v2 = acc[mt][2][r], v3 = acc[mt][3][r];
        float s = (v0 + v1) + (v2 + v3);
        float q = fmaf(v0, v0, fmaf(v1, v1, fmaf(v2, v2, v3 * v3)));
        s += dpp_f32<0x128>(s); q += dpp_f32<0x128>(q);
        s += dpp_f32<0x124>(s); q += dpp_f32<0x124>(q);
        s += dpp_f32<0x122>(s); q += dpp_f32<0x122>(q);
        s += dpp_f32<0x121>(s); q += dpp_f32<0x121>(q);
        const float mu = s * 0.015625f;
        const float var = q * 0.015625f - mu * mu;
        const float rs = rsqrtf(var + EPS);
        const int row = R0 + 16*mt + 4*gq + r;
        short* xsw = (short*)Xw + row * 104;
#pragma unroll
        for (int nt = 0; nt < 4; ++nt) {
          const float y = fmaxf((acc[mt][nt][r] - mu) * rs * gg[nt] + bb[nt], 0.0f);
          xsw[16*nt + c] = (short)bf16s(y);
        }
      }
    }
  }

  // ================= layer 3: N=128 in two 64-col halves + maxpool =======
  float* og = out + (size_t)(g0 + wid) * OUTn;
#pragma unroll
  for (int h = 0; h < 2; ++h) {
#pragma unroll
    for (int nt = 0; nt < 4; ++nt) {
      const float bv = bout[64*h + 16*nt + c];
      acc[0][nt] = (f32x4){bv, bv, bv, bv};
      acc[1][nt] = (f32x4){bv, bv, bv, bv};
    }
#pragma unroll
    for (int ks = 0; ks < 2; ++ks) {
      const bf16x8 af0 = *(const bf16x8*)(xs_base + (R0 +      c) * 104 + 32*ks + 8*gq);
      const bf16x8 af1 = *(const bf16x8*)(xs_base + (R0 + 16 + c) * 104 + 32*ks + 8*gq);
#pragma unroll
      for (int nt = 0; nt < 4; ++nt) {
        const bf16x8 bf = *(const bf16x8*)(w3b + (size_t)(64*h + 16*nt + c) * 64 + 32*ks + 8*gq);
        acc[0][nt] = __builtin_amdgcn_mfma_f32_16x16x32_bf16(af0, bf, acc[0][nt], 0, 0, 0);
        acc[1][nt] = __builtin_amdgcn_mfma_f32_16x16x32_bf16(af1, bf, acc[1][nt], 0, 0, 0);
      }
    }
#pragma unroll
    for (int nt = 0; nt < 4; ++nt) {
      float m0 = fmaxf(fmaxf(acc[0][nt][0], acc[0][nt][1]),
                       fmaxf(acc[0][nt][2], acc[0][nt][3]));
      float m1 = fmaxf(fmaxf(acc[1][nt][0], acc[1][nt][1]),
                       fmaxf(acc[1][nt][2], acc[1][nt][3]));
      float m = fmaxf(m0, m1);
      m = fmaxf(m, __shfl_xor(m, 16));
      m = fmaxf(m, __shfl_xor(m, 32));
      if (gq == 0) og[64*h + 16*nt + c] = m;
    }
  }
}

// ---------------------------------------------------------------------------
extern "C" void kernel_launch(void* const* d_in, const int* in_sizes, int n_in,
                              void* d_out, int out_size, void* d_ws, size_t ws_size,
                              hipStream_t stream)
{
  const float* xyz  = (const float*)d_in[0];
  const float* feat = (const float*)d_in[1];
  const float* W1   = (const float*)d_in[2];
  const float* b1   = (const float*)d_in[3];
  const float* g1   = (const float*)d_in[4];
  const float* be1  = (const float*)d_in[5];
  const float* W2   = (const float*)d_in[6];
  const float* b2   = (const float*)d_in[7];
  const float* g2   = (const float*)d_in[8];
  const float* be2  = (const float*)d_in[9];
  const float* Wout = (const float*)d_in[10];
  const float* bout = (const float*)d_in[11];

  float* outp = (float*)d_out;
  float* cent = outp;                             // (B, M, 3)
  float* o    = outp + (size_t)Bn * Mn * 3;       // (B, M, 128)

  u16*  wb = (u16*)d_ws;                          // 36864 B
  const size_t P4_OFF = 36864;                    // 16B-aligned
  float4* p4 = (float4*)((char*)d_ws + P4_OFF);   // 1 MB

  const int prep_total = WB_N + P4_N;             // 18432 + 65536
  prep_kernel<<<(prep_total + 255) / 256, 256, 0, stream>>>(
      W1, W2, Wout, wb, xyz, p4);
  fps_kernel<<<Bn, 256, 0, stream>>>(p4, cent);
  knn4_kernel<<<Bn * Mn / 4, 256, 0, stream>>>(p4, cent, (int*)o);
  mlp_kernel<<<Bn * Mn / 4, 256, 0, stream>>>(p4, feat, wb,
                                              b1, g1, be1,
                                              b2, g2, be2, bout,
                                              cent, o);
}

// Round 20
// 913.777 us; speedup vs baseline: 1.0169x; 1.0169x over previous
//
#include <hip/hip_runtime.h>
#include <math.h>

#define Bn   16
#define Nn   4096
#define Cn   64
#define Mn   1024
#define Kn   32
#define OUTn 128
#define EPS  1e-5f

typedef unsigned long long u64;
typedef unsigned int u32;
typedef unsigned short u16;
typedef __attribute__((ext_vector_type(8))) short bf16x8;
typedef __attribute__((ext_vector_type(4))) float f32x4;

__device__ __forceinline__ u64 u64min(u64 a, u64 b) { return a < b ? a : b; }
__device__ __forceinline__ u64 u64max(u64 a, u64 b) { return a > b ? a : b; }

template<int CTRL>
__device__ __forceinline__ u64 dpp_u64(u64 x) {
  union { u64 q; u32 w[2]; } in, out;
  in.q = x;
  out.w[0] = (u32)__builtin_amdgcn_update_dpp((int)in.w[0], (int)in.w[0], CTRL, 0xf, 0xf, false);
  out.w[1] = (u32)__builtin_amdgcn_update_dpp((int)in.w[1], (int)in.w[1], CTRL, 0xf, 0xf, false);
  return out.q;
}
// f32 DPP move (old = x, full masks). row_ror:N = 0x120|N operates within
// 16-lane rows -> rotation allreduce for our 16-lane LN groups.
template<int CTRL>
__device__ __forceinline__ float dpp_f32(float x) {
  return __uint_as_float((u32)__builtin_amdgcn_update_dpp(
      (int)__float_as_uint(x), (int)__float_as_uint(x), CTRL, 0xf, 0xf, false));
}

__device__ __forceinline__ u64 wave_max_dpp(u64 v) {
  v = u64max(v, dpp_u64<0x111>(v));
  v = u64max(v, dpp_u64<0x112>(v));
  v = u64max(v, dpp_u64<0x114>(v));
  v = u64max(v, dpp_u64<0x118>(v));
  v = u64max(v, dpp_u64<0x142>(v));
  v = u64max(v, dpp_u64<0x143>(v));
  return v;
}
__device__ __forceinline__ u64 wave_min_dpp(u64 v) {
  v = u64min(v, dpp_u64<0x111>(v));
  v = u64min(v, dpp_u64<0x112>(v));
  v = u64min(v, dpp_u64<0x114>(v));
  v = u64min(v, dpp_u64<0x118>(v));
  v = u64min(v, dpp_u64<0x142>(v));
  v = u64min(v, dpp_u64<0x143>(v));
  return v;
}

// RTN f32->bf16 pack helpers
__device__ __forceinline__ u32 rnd2(float a, float b) {
  u32 ua = __float_as_uint(a);
  ua = (ua + 0x7FFFu + ((ua >> 16) & 1u)) >> 16;
  u32 ub = __float_as_uint(b);
  ub = (ub + 0x7FFFu + ((ub >> 16) & 1u)) & 0xFFFF0000u;
  return ua | ub;
}
__device__ __forceinline__ u16 bf16s(float a) {
  u32 ua = __float_as_uint(a);
  return (u16)((ua + 0x7FFFu + ((ua >> 16) & 1u)) >> 16);
}

// ---------------------------------------------------------------------------
// Weight pre-conversion (r17, unchanged): f32 -> bf16 RTN, fragment k-order.
// ---------------------------------------------------------------------------
__global__ __launch_bounds__(256) void wconv_kernel(
    const float* __restrict__ W1, const float* __restrict__ W2,
    const float* __restrict__ Wout, u16* __restrict__ wb)
{
  const int i = blockIdx.x * 256 + threadIdx.x;   // 0 .. 18431
  float v;
  if (i < 6144) {
    const int r = i / 96, k = i % 96;
    v = (k < 64) ? W1[r * 67 + 3 + k] : (k < 67 ? W1[r * 67 + (k - 64)] : 0.0f);
  } else if (i < 10240) {
    v = W2[i - 6144];
  } else {
    v = Wout[i - 10240];
  }
  wb[i] = bf16s(v);
}

// ---------------------------------------------------------------------------
// Point pre-pack: xyz (B,N,3) -> float4 array in ws. Exact copies (no
// rounding) -> knn keys bit-identical; loads become coalesced dwordx4.
// ---------------------------------------------------------------------------
__global__ __launch_bounds__(256) void pconv_kernel(
    const float* __restrict__ xyz, float4* __restrict__ p4)
{
  const int i = blockIdx.x * 256 + threadIdx.x;   // 0 .. 65535
  p4[i] = make_float4(xyz[3*i+0], xyz[3*i+1], xyz[3*i+2], 0.0f);
}

// ---------------------------------------------------------------------------
// FPS: r13 version, byte-identical (best measured: 647 us; restructure
// attempts r7/r8/r11/r19 all regressed or neutral -> measured floor).
// ---------------------------------------------------------------------------
__global__ __launch_bounds__(256) void fps_kernel(
    const float* __restrict__ xyz, float* __restrict__ cent)
{
  __shared__ float4 pts4[Nn];          // 64 KB
  __shared__ __align__(16) u64 pvq[2][4];

  const int b = blockIdx.x;
  const int t = threadIdx.x;
  const float* src = xyz + (size_t)b * Nn * 3;

  for (int i = t; i < Nn; i += 256) {
    pts4[i] = make_float4(src[3*i+0], src[3*i+1], src[3*i+2], 0.0f);
  }
  __syncthreads();

  const float4 c0 = pts4[0];

  float px[16], py[16], pz[16], d[16];
  u32 ninv[16];
#pragma unroll
  for (int j = 0; j < 16; ++j) {
    const int n = j * 256 + t;
    ninv[j] = (u32)(~n);
    const float4 p = pts4[n];
    px[j] = p.x; py[j] = p.y; pz[j] = p.z;
    const float dx = px[j] - c0.x, dy = py[j] - c0.y, dz = pz[j] - c0.z;
    d[j] = (dx * dx + dy * dy) + dz * dz;
  }

  if (t == 0) {
    float* o = cent + (size_t)b * Mn * 3;
    o[0] = c0.x; o[1] = c0.y; o[2] = c0.z;
  }

  for (int m = 1; m < Mn; ++m) {
    u64 k[16];
#pragma unroll
    for (int j = 0; j < 16; ++j)
      k[j] = ((u64)__float_as_uint(d[j]) << 32) | ninv[j];
#pragma unroll
    for (int st = 1; st < 16; st <<= 1)
#pragma unroll
      for (int j = 0; j < 16; j += (st << 1))
        k[j] = u64max(k[j], k[j + st]);

    const u64 bk = wave_max_dpp(k[0]);
    const int par = m & 1;
    if ((t & 63) == 63) pvq[par][t >> 6] = bk;
    __syncthreads();

    const u64 f = u64max(u64max(pvq[par][0], pvq[par][1]),
                         u64max(pvq[par][2], pvq[par][3]));
    const int fi = (int)(~(u32)f);

    const float4 cp = pts4[fi];
    if (t == 0) {
      float* o = cent + ((size_t)b * Mn + m) * 3;
      o[0] = cp.x; o[1] = cp.y; o[2] = cp.z;
    }

#pragma unroll
    for (int j = 0; j < 16; ++j) {
      const float dx = px[j] - cp.x, dy = py[j] - cp.y, dz = pz[j] - cp.z;
      const float nd = (dx * dx + dy * dy) + dz * dz;
      d[j] = fminf(d[j], nd);
    }
  }
}

// ---------------------------------------------------------------------------
// KNN core (templated on point source). One wave per centroid, zero LDS,
// zero barriers. Keys (mono(bits(d2))<<32)|n; u64 MIN == stable top_k set.
// ---------------------------------------------------------------------------
template<bool USE_P4>
__device__ __forceinline__ void knn_body(
    const float* __restrict__ P, const float4* __restrict__ P4,
    const float* __restrict__ cent, int* __restrict__ osel,
    int g, int lane)
{
  const float cx = cent[(size_t)g * 3 + 0];
  const float cy = cent[(size_t)g * 3 + 1];
  const float cz = cent[(size_t)g * 3 + 2];
  const float cc2 = (cx * cx + cy * cy) + cz * cz;

  u64 kk[4][16];
  u64 gm0, gm1, gm2, gm3;

#pragma unroll
  for (int grp = 0; grp < 4; ++grp) {
#pragma unroll
    for (int j = 0; j < 16; ++j) {
      const int n = grp * 1024 + j * 64 + lane;
      float x, y, z;
      if (USE_P4) {
        const float4 p = P4[n];
        x = p.x; y = p.y; z = p.z;
      } else {
        x = P[n*3+0]; y = P[n*3+1]; z = P[n*3+2];
      }
      const float pp = (x * x + y * y) + z * z;
      const float dt = (cx * x + cy * y) + cz * z;
      const float d2 = (cc2 + pp) - 2.0f * dt;
      const u32 bu = __float_as_uint(d2);
      const u32 mo = bu ^ (0x80000000u | (u32)((int)bu >> 31));
      kk[grp][j] = ((u64)mo << 32) | (u32)n;
    }
  }
#define TREE16(dst, A_)                                                 \
  {                                                                     \
    u64 t0 = u64min(A_[0], A_[1]),  t1 = u64min(A_[2], A_[3]);          \
    u64 t2 = u64min(A_[4], A_[5]),  t3 = u64min(A_[6], A_[7]);          \
    u64 t4 = u64min(A_[8], A_[9]),  t5 = u64min(A_[10], A_[11]);        \
    u64 t6 = u64min(A_[12], A_[13]), t7 = u64min(A_[14], A_[15]);       \
    t0 = u64min(t0, t1); t2 = u64min(t2, t3);                           \
    t4 = u64min(t4, t5); t6 = u64min(t6, t7);                           \
    dst = u64min(u64min(t0, t2), u64min(t4, t6));                       \
  }
  TREE16(gm0, kk[0]); TREE16(gm1, kk[1]);
  TREE16(gm2, kk[2]); TREE16(gm3, kk[3]);
  u64 bk = u64min(u64min(gm0, gm1), u64min(gm2, gm3));

  int myfi = 0;
  for (int s = 0; s < Kn; ++s) {
    const u64 v = wave_min_dpp(bk);
    const u32 flo = (u32)__builtin_amdgcn_readlane((int)(u32)v, 63);
    const int fi = (int)flo;
    if (lane == s) myfi = fi;

    const int og = __builtin_amdgcn_readfirstlane(fi >> 10);
    const int oj = __builtin_amdgcn_readfirstlane((fi >> 6) & 15);
    if (lane == (fi & 63)) {
#pragma unroll
      for (int grp = 0; grp < 4; ++grp) {
        if (grp == og) {
#pragma unroll
          for (int j = 0; j < 16; ++j)
            if (j == oj) kk[grp][j] = ~0ull;
          u64 nm;
          TREE16(nm, kk[grp]);
          if (grp == 0) gm0 = nm;
          else if (grp == 1) gm1 = nm;
          else if (grp == 2) gm2 = nm;
          else gm3 = nm;
        }
      }
      bk = u64min(u64min(gm0, gm1), u64min(gm2, gm3));
    }
  }
#undef TREE16

  if (lane < Kn) osel[(size_t)g * 128 + lane] = myfi;
}

__global__ __launch_bounds__(256) void knn_kernel(
    const float* __restrict__ xyz, const float* __restrict__ cent,
    int* __restrict__ osel)
{
  const int t    = threadIdx.x;
  const int lane = t & 63;
  const int wid  = __builtin_amdgcn_readfirstlane(t >> 6);
  const int g    = (blockIdx.x << 2) + wid;
  const int b    = g >> 10;
  knn_body<false>(xyz + (size_t)b * Nn * 3, nullptr, cent, osel, g, lane);
}

__global__ __launch_bounds__(256) void knn4_kernel(
    const float4* __restrict__ p4, const float* __restrict__ cent,
    int* __restrict__ osel)
{
  const int t    = threadIdx.x;
  const int lane = t & 63;
  const int wid  = __builtin_amdgcn_readfirstlane(t >> 6);
  const int g    = (blockIdx.x << 2) + wid;
  const int b    = g >> 10;
  knn_body<true>(nullptr, p4 + (size_t)b * Nn, cent, osel, g, lane);
}

// ---------------------------------------------------------------------------
// MLP via bf16 MFMA (r17 structure). LN 16-lane reductions use DPP rotation
// allreduce (row_ror 8/4/2/1). Weights pre-converted (wconv). One block per
// 4 centroids; wave w owns centroid w (32 rows x 64 cols): LN + maxpool
// fully in-wave, ONE barrier total.
// ---------------------------------------------------------------------------
__global__ __launch_bounds__(256) void mlp_kernel(
    const float* __restrict__ xyz, const float* __restrict__ feat,
    const u16* __restrict__ wb,
    const float* __restrict__ b1, const float* __restrict__ g1,
    const float* __restrict__ be1,
    const float* __restrict__ b2, const float* __restrict__ g2,
    const float* __restrict__ be2, const float* __restrict__ bout,
    const float* __restrict__ cent, float* __restrict__ out)
{
  __shared__ u32 Xw[128][52];        // 128 rows x 104 bf16 (26.6 KB)

  const int g0   = blockIdx.x << 2;
  const int b    = g0 >> 10;
  const int t    = threadIdx.x;
  const int wid  = __builtin_amdgcn_readfirstlane(t >> 6);
  const int lane = t & 63;

  const float* P = xyz  + (size_t)b * Nn * 3;
  const float* F = feat + (size_t)b * Nn * Cn;
  const int* osel = (const int*)out;

  const u16* w1b = wb;               // [64][96]
  const u16* w2b = wb + 6144;        // [64][64]
  const u16* w3b = wb + 10240;       // [128][64]

  // ---- gather -> bf16 LDS (2 threads per row) ----
  {
    const int row = t >> 1, half = t & 1;
    const int gi = g0 + (row >> 5);
    const int n = osel[(size_t)gi * 128 + (row & 31)];
    const float* fr = F + (size_t)n * Cn + 32 * half;
#pragma unroll
    for (int q = 0; q < 4; ++q) {
      const float4 a = ((const float4*)fr)[2*q];
      const float4 c = ((const float4*)fr)[2*q+1];
      uint4 wv;
      wv.x = rnd2(a.x, a.y); wv.y = rnd2(a.z, a.w);
      wv.z = rnd2(c.x, c.y); wv.w = rnd2(c.z, c.w);
      *(uint4*)&Xw[row][16*half + 4*q] = wv;
    }
    if (half) {
      const float pxc = P[n*3+0] - cent[(size_t)gi*3+0];
      const float pyc = P[n*3+1] - cent[(size_t)gi*3+1];
      const float pzc = P[n*3+2] - cent[(size_t)gi*3+2];
      Xw[row][32] = rnd2(pxc, pyc);
      Xw[row][33] = rnd2(pzc, 0.0f);
      Xw[row][34] = 0; Xw[row][35] = 0;
#pragma unroll
      for (int q2 = 0; q2 < 4; ++q2) {
        uint4 z; z.x = z.y = z.z = z.w = 0;
        *(uint4*)&Xw[row][36 + 4*q2] = z;
      }
    }
  }
  __syncthreads();

  const int c  = lane & 15;          // frag col / A-row low
  const int gq = lane >> 4;          // frag k-group / C-row group
  const int R0 = wid << 5;           // wave's first row (centroid wid)
  const short* xs_base = (const short*)Xw;

  f32x4 acc[2][4];

  // ================= layer 1: K=96 (feats | coords | pad) ==============
#pragma unroll
  for (int nt = 0; nt < 4; ++nt) {
    const float bv = b1[16*nt + c];
    acc[0][nt] = (f32x4){bv, bv, bv, bv};
    acc[1][nt] = (f32x4){bv, bv, bv, bv};
  }
#pragma unroll
  for (int ks = 0; ks < 3; ++ks) {
    const bf16x8 af0 = *(const bf16x8*)(xs_base + (R0 +      c) * 104 + 32*ks + 8*gq);
    const bf16x8 af1 = *(const bf16x8*)(xs_base + (R0 + 16 + c) * 104 + 32*ks + 8*gq);
#pragma unroll
    for (int nt = 0; nt < 4; ++nt) {
      const bf16x8 bf = *(const bf16x8*)(w1b + (16*nt + c) * 96 + 32*ks + 8*gq);
      acc[0][nt] = __builtin_amdgcn_mfma_f32_16x16x32_bf16(af0, bf, acc[0][nt], 0, 0, 0);
      acc[1][nt] = __builtin_amdgcn_mfma_f32_16x16x32_bf16(af1, bf, acc[1][nt], 0, 0, 0);
    }
  }

  // ---- LN1 + ReLU (DPP rotation allreduce) -> Xw bf16 cols 0..63 ----
  {
    float gg[4], bb[4];
#pragma unroll
    for (int nt = 0; nt < 4; ++nt) { gg[nt] = g1[16*nt + c]; bb[nt] = be1[16*nt + c]; }
#pragma unroll
    for (int mt = 0; mt < 2; ++mt) {
#pragma unroll
      for (int r = 0; r < 4; ++r) {
        const float v0 = acc[mt][0][r], v1 = acc[mt][1][r];
        const float v2 = acc[mt][2][r], v3 = acc[mt][3][r];
        float s = (v0 + v1) + (v2 + v3);
        float q = fmaf(v0, v0, fmaf(v1, v1, fmaf(v2, v2, v3 * v3)));
        s += dpp_f32<0x128>(s); q += dpp_f32<0x128>(q);   // row_ror:8
        s += dpp_f32<0x124>(s); q += dpp_f32<0x124>(q);   // row_ror:4
        s += dpp_f32<0x122>(s); q += dpp_f32<0x122>(q);   // row_ror:2
        s += dpp_f32<0x121>(s); q += dpp_f32<0x121>(q);   // row_ror:1
        const float mu = s * 0.015625f;
        const float var = q * 0.015625f - mu * mu;
        const float rs = rsqrtf(var + EPS);
        const int row = R0 + 16*mt + 4*gq + r;
        short* xsw = (short*)Xw + row * 104;
#pragma unroll
        for (int nt = 0; nt < 4; ++nt) {
          const float y = fmaxf((acc[mt][nt][r] - mu) * rs * gg[nt] + bb[nt], 0.0f);
          xsw[16*nt + c] = (short)bf16s(y);
        }
      }
    }
  }

  // ================= layer 2: K=64 =================
#pragma unroll
  for (int nt = 0; nt < 4; ++nt) {
    const float bv = b2[16*nt + c];
    acc[0][nt] = (f32x4){bv, bv, bv, bv};
    acc[1][nt] = (f32x4){bv, bv, bv, bv};
  }
#pragma unroll
  for (int ks = 0; ks < 2; ++ks) {
    const bf16x8 af0 = *(const bf16x8*)(xs_base + (R0 +      c) * 104 + 32*ks + 8*gq);
    const bf16x8 af1 = *(const bf16x8*)(xs_base + (R0 + 16 + c) * 104 + 32*ks + 8*gq);
#pragma unroll
    for (int nt = 0; nt < 4; ++nt) {
      const bf16x8 bf = *(const bf16x8*)(w2b + (16*nt + c) * 64 + 32*ks + 8*gq);
      acc[0][nt] = __builtin_amdgcn_mfma_f32_16x16x32_bf16(af0, bf, acc[0][nt], 0, 0, 0);
      acc[1][nt] = __builtin_amdgcn_mfma_f32_16x16x32_bf16(af1, bf, acc[1][nt], 0, 0, 0);
    }
  }

  // ---- LN2 + ReLU (DPP rotation allreduce) -> Xw bf16 cols 0..63 ----
  {
    float gg[4], bb[4];
#pragma unroll
    for (int nt = 0; nt < 4; ++nt) { gg[nt] = g2[16*nt + c]; bb[nt] = be2[16*nt + c]; }
#pragma unroll
    for (int mt = 0; mt < 2; ++mt) {
#pragma unroll
      for (int r = 0; r < 4; ++r) {
        const float v0 = acc[mt][0][r], v1 = acc[mt][1][r];
        const float v2 = acc[mt][2][r], v3 = acc[mt][3][r];
        float s = (v0 + v1) + (v2 + v3);
        float q = fmaf(v0, v0, fmaf(v1, v1, fmaf(v2, v2, v3 * v3)));
        s += dpp_f32<0x128>(s); q += dpp_f32<0x128>(q);
        s += dpp_f32<0x124>(s); q += dpp_f32<0x124>(q);
        s += dpp_f32<0x122>(s); q += dpp_f32<0x122>(q);
        s += dpp_f32<0x121>(s); q += dpp_f32<0x121>(q);
        const float mu = s * 0.015625f;
        const float var = q * 0.015625f - mu * mu;
        const float rs = rsqrtf(var + EPS);
        const int row = R0 + 16*mt + 4*gq + r;
        short* xsw = (short*)Xw + row * 104;
#pragma unroll
        for (int nt = 0; nt < 4; ++nt) {
          const float y = fmaxf((acc[mt][nt][r] - mu) * rs * gg[nt] + bb[nt], 0.0f);
          xsw[16*nt + c] = (short)bf16s(y);
        }
      }
    }
  }

  // ================= layer 3: N=128 in two 64-col halves + maxpool =======
  float* og = out + (size_t)(g0 + wid) * OUTn;
#pragma unroll
  for (int h = 0; h < 2; ++h) {
#pragma unroll
    for (int nt = 0; nt < 4; ++nt) {
      const float bv = bout[64*h + 16*nt + c];
      acc[0][nt] = (f32x4){bv, bv, bv, bv};
      acc[1][nt] = (f32x4){bv, bv, bv, bv};
    }
#pragma unroll
    for (int ks = 0; ks < 2; ++ks) {
      const bf16x8 af0 = *(const bf16x8*)(xs_base + (R0 +      c) * 104 + 32*ks + 8*gq);
      const bf16x8 af1 = *(const bf16x8*)(xs_base + (R0 + 16 + c) * 104 + 32*ks + 8*gq);
#pragma unroll
      for (int nt = 0; nt < 4; ++nt) {
        const bf16x8 bf = *(const bf16x8*)(w3b + (size_t)(64*h + 16*nt + c) * 64 + 32*ks + 8*gq);
        acc[0][nt] = __builtin_amdgcn_mfma_f32_16x16x32_bf16(af0, bf, acc[0][nt], 0, 0, 0);
        acc[1][nt] = __builtin_amdgcn_mfma_f32_16x16x32_bf16(af1, bf, acc[1][nt], 0, 0, 0);
      }
    }
#pragma unroll
    for (int nt = 0; nt < 4; ++nt) {
      float m0 = fmaxf(fmaxf(acc[0][nt][0], acc[0][nt][1]),
                       fmaxf(acc[0][nt][2], acc[0][nt][3]));
      float m1 = fmaxf(fmaxf(acc[1][nt][0], acc[1][nt][1]),
                       fmaxf(acc[1][nt][2], acc[1][nt][3]));
      float m = fmaxf(m0, m1);
      m = fmaxf(m, __shfl_xor(m, 16));
      m = fmaxf(m, __shfl_xor(m, 32));
      if (gq == 0) og[64*h + 16*nt + c] = m;
    }
  }
}

// ---------------------------------------------------------------------------
extern "C" void kernel_launch(void* const* d_in, const int* in_sizes, int n_in,
                              void* d_out, int out_size, void* d_ws, size_t ws_size,
                              hipStream_t stream)
{
  const float* xyz  = (const float*)d_in[0];
  const float* feat = (const float*)d_in[1];
  const float* W1   = (const float*)d_in[2];
  const float* b1   = (const float*)d_in[3];
  const float* g1   = (const float*)d_in[4];
  const float* be1  = (const float*)d_in[5];
  const float* W2   = (const float*)d_in[6];
  const float* b2   = (const float*)d_in[7];
  const float* g2   = (const float*)d_in[8];
  const float* be2  = (const float*)d_in[9];
  const float* Wout = (const float*)d_in[10];
  const float* bout = (const float*)d_in[11];

  float* outp = (float*)d_out;
  float* cent = outp;                             // (B, M, 3)
  float* o    = outp + (size_t)Bn * Mn * 3;       // (B, M, 128)

  u16*  wb = (u16*)d_ws;                          // 36864 B
  const size_t P4_OFF = 36864;                    // 16B-aligned
  float4* p4 = (float4*)((char*)d_ws + P4_OFF);   // 1 MB
  const bool use_p4 = ws_size >= P4_OFF + (size_t)Bn * Nn * sizeof(float4);

  wconv_kernel<<<72, 256, 0, stream>>>(W1, W2, Wout, wb);
  if (use_p4)
    pconv_kernel<<<Bn * Nn / 256, 256, 0, stream>>>(xyz, p4);
  fps_kernel<<<Bn, 256, 0, stream>>>(xyz, cent);
  if (use_p4)
    knn4_kernel<<<Bn * Mn / 4, 256, 0, stream>>>(p4, cent, (int*)o);
  else
    knn_kernel<<<Bn * Mn / 4, 256, 0, stream>>>(xyz, cent, (int*)o);
  mlp_kernel<<<Bn * Mn / 4, 256, 0, stream>>>(xyz, feat, wb,
                                              b1, g1, be1,
                                              b2, g2, be2, bout,
                                              cent, o);
}